// Round 4
// baseline (61.454 us; speedup 1.0000x reference)
//
#include <hip/hip_runtime.h>
#include <hip/hip_bf16.h>
#include <stdint.h>

// Problem: B=32, N=4096, D=256, F=256
//   x = relu(A @ W + bias)            A:[B,F] W:[F,N] -> x:[B,N]
//   mask = x > threshold
//   out[b] = stable-compact(raw_input[b] rows where mask), zero-padded to N.
//
// 2 kernels: (1) tiny GEMM -> packed bit-mask [B, N/16] u16;
//            (2) fused per-block scan + row gather (scan recomputed per block
//                from the 16KB bit array -- L2-resident, hides under HBM).

#define BB 32
#define NN 4096
#define DD 256
#define FF 256
#define COLS 16            // W columns per chunk
#define CH (NN / COLS)     // 256 chunks
#define ASTRIDE (FF + 4)   // padded LDS stride (260 floats, 16B-aligned)
#define ROWS_PER_BLK 8     // gather: dst rows per block (4 waves x 2)

typedef float f4 __attribute__((ext_vector_type(4)));

// ---------------- Kernel 1: tiny GEMM -> packed 16-bit masks ----------------
// Grid CH=256 blocks x 256 threads. Block owns 16 columns x all 32 batches.
// W read exactly once from HBM (4 MB). A (32 KB) + W-chunk staged in LDS,
// read as float4. f64 accumulation: a mask flip vs the f32 reference shifts
// whole output rows -> absmax ~5. f64 keeps us exact (validated absmax=0).
__global__ __launch_bounds__(256) void mask_kernel(
    const float* __restrict__ A,      // [B,F]
    const float* __restrict__ W,      // [F,N]
    const float* __restrict__ bias,   // [N]
    const float* __restrict__ thr_p,  // [1]
    uint16_t* __restrict__ bits)      // [B,CH]
{
    __shared__ float a_sh[BB * ASTRIDE];
    __shared__ float wT[COLS * ASTRIDE];

    const int t     = threadIdx.x;
    const int chunk = blockIdx.x;
    const int n0    = chunk * COLS;

    for (int i = t; i < BB * FF; i += 256) {
        int b = i >> 8, f = i & 255;
        a_sh[b * ASTRIDE + f] = A[i];
    }
    for (int i = t; i < FF * COLS; i += 256) {
        int f = i >> 4, c = i & 15;
        wT[c * ASTRIDE + f] = W[(size_t)f * NN + n0 + c];
    }
    __syncthreads();

    const float thr = thr_p[0];
    const int c  = t & 15;
    const int b1 = t >> 4;        // 0..15
    const int b2 = b1 + 16;       // 16..31

    const f4* a1p = reinterpret_cast<const f4*>(a_sh + b1 * ASTRIDE);
    const f4* a2p = reinterpret_cast<const f4*>(a_sh + b2 * ASTRIDE);
    const f4* wp  = reinterpret_cast<const f4*>(wT   + c  * ASTRIDE);

    double s0 = 0.0, s1 = 0.0, s2 = 0.0, s3 = 0.0;
    #pragma unroll 8
    for (int fs = 0; fs < FF / 4; ++fs) {
        f4 w4 = wp[fs];
        f4 a1 = a1p[fs];
        f4 a2 = a2p[fs];
        s0 = fma((double)a1.x, (double)w4.x, s0);
        s0 = fma((double)a1.y, (double)w4.y, s0);
        s1 = fma((double)a1.z, (double)w4.z, s1);
        s1 = fma((double)a1.w, (double)w4.w, s1);
        s2 = fma((double)a2.x, (double)w4.x, s2);
        s2 = fma((double)a2.y, (double)w4.y, s2);
        s3 = fma((double)a2.z, (double)w4.z, s3);
        s3 = fma((double)a2.w, (double)w4.w, s3);
    }
    const float bi = bias[n0 + c];
    const float v1 = (float)(s0 + s1) + bi;
    const float v2 = (float)(s2 + s3) + bi;
    const int m1 = (fmaxf(v1, 0.f) > thr) ? 1 : 0;
    const int m2 = (fmaxf(v2, 0.f) > thr) ? 1 : 0;

    unsigned long long bal1 = __ballot(m1);
    unsigned long long bal2 = __ballot(m2);
    if (c == 0) {
        const int g = (t & 63) >> 4;
        bits[b1 * CH + chunk] = (uint16_t)((bal1 >> (16 * g)) & 0xFFFF);
        bits[b2 * CH + chunk] = (uint16_t)((bal2 >> (16 * g)) & 0xFFFF);
    }
}

// ---------------- Kernel 2: fused scan + gather ------------------------------
// Grid (N/8 = 512, B) x 256 threads. Each block redundantly scans its batch's
// 256 packed chunks (512 B, L2-resident) to find the source rows for its 8
// destination rows, then 4 waves each copy/zero 2 rows (64 lanes x float4).
__global__ __launch_bounds__(256) void gather_kernel(
    const float* __restrict__ raw,     // [B,N,D]
    const uint16_t* __restrict__ bits, // [B,CH]
    float* __restrict__ out)           // [B,N,D]
{
    const int b   = blockIdx.y;
    const int t   = threadIdx.x;
    const int j0b = blockIdx.x * ROWS_PER_BLK;

    __shared__ int wsum[4];
    __shared__ int cnt_sh;
    __shared__ int order_sh[ROWS_PER_BLK];

    // --- per-block scan over the batch's packed mask ---
    unsigned m = bits[b * CH + t];      // thread t owns chunk t (16 columns)
    const int s = __popc(m);

    const int lane = t & 63;
    const int wid  = t >> 6;
    int incl = s;
    #pragma unroll
    for (int d = 1; d < 64; d <<= 1) {
        int x = __shfl_up(incl, d, 64);
        if (lane >= d) incl += x;
    }
    if (lane == 63) wsum[wid] = incl;
    __syncthreads();
    if (t == 0) {
        int run = 0;
        #pragma unroll
        for (int i = 0; i < 4; ++i) { int x = wsum[i]; wsum[i] = run; run += x; }
        cnt_sh = run;
    }
    __syncthreads();

    int base = wsum[wid] + (incl - s);  // stable exclusive prefix for chunk t
    // expand only the bits that land in this block's dst range [j0b, j0b+8)
    if (base < j0b + ROWS_PER_BLK && base + s > j0b) {
        const int n0 = t * COLS;
        while (m) {
            const int pos = __ffs(m) - 1;
            const unsigned rel = (unsigned)(base - j0b);
            if (rel < ROWS_PER_BLK) order_sh[rel] = n0 + pos;
            ++base;
            if (base >= j0b + ROWS_PER_BLK) break;
            m &= m - 1;
        }
    }
    __syncthreads();

    // --- gather/zero: wave wid handles dst rows j0b + wid*2 + {0,1} ---
    const int cnt = cnt_sh;
    const f4* rawp = reinterpret_cast<const f4*>(raw);
    f4* outp = reinterpret_cast<f4*>(out);
    const int j0 = j0b + wid * 2;

    f4 r0 = {0.f, 0.f, 0.f, 0.f};
    f4 r1 = {0.f, 0.f, 0.f, 0.f};
    if (j0 < cnt) {
        const int src = order_sh[j0 - j0b];
        r0 = __builtin_nontemporal_load(rawp + ((size_t)b * NN + src) * (DD / 4) + lane);
    }
    if (j0 + 1 < cnt) {
        const int src = order_sh[j0 + 1 - j0b];
        r1 = __builtin_nontemporal_load(rawp + ((size_t)b * NN + src) * (DD / 4) + lane);
    }
    __builtin_nontemporal_store(r0, outp + ((size_t)b * NN + j0)     * (DD / 4) + lane);
    __builtin_nontemporal_store(r1, outp + ((size_t)b * NN + j0 + 1) * (DD / 4) + lane);
}

extern "C" void kernel_launch(void* const* d_in, const int* in_sizes, int n_in,
                              void* d_out, int out_size, void* d_ws, size_t ws_size,
                              hipStream_t stream) {
    const float* raw  = (const float*)d_in[0];   // [B,N,D]
    const float* A    = (const float*)d_in[1];   // [B,F]
    const float* W    = (const float*)d_in[2];   // [F,N]
    const float* bias = (const float*)d_in[3];   // [N]
    const float* thr  = (const float*)d_in[4];   // [1]
    float* out = (float*)d_out;

    uint16_t* bits = (uint16_t*)d_ws;            // B*CH*2 = 16 KB

    mask_kernel<<<CH, 256, 0, stream>>>(A, W, bias, thr, bits);
    gather_kernel<<<dim3(NN / ROWS_PER_BLK, BB), 256, 0, stream>>>(raw, bits, out);
}

// Round 5
// 55.848 us; speedup vs baseline: 1.1004x; 1.1004x over previous
//
#include <hip/hip_runtime.h>
#include <hip/hip_bf16.h>
#include <stdint.h>

// Problem: B=32, N=4096, D=256, F=256
//   x = relu(A @ W + bias)            A:[B,F] W:[F,N] -> x:[B,N]
//   mask = x > threshold
//   out[b] = stable-compact(raw_input[b] rows where mask), zero-padded to N.
//
// Kernel 1: tiny GEMM -> packed bit-mask, stored as bytes [B][512] (8 cols
//           per chunk), read later as u16 [B][256] (little-endian identity).
// Kernel 2: fused per-block scan + gather, 32 dst rows per block.

#define BB 32
#define NN 4096
#define DD 256
#define FF 256
#define ASTRIDE (FF + 4)   // padded LDS stride
#define RPB 32             // gather: dst rows per block (4 waves x 8)

typedef float f4 __attribute__((ext_vector_type(4)));

// ---------------- Kernel 1: tiny GEMM -> packed masks -----------------------
// Grid 512 blocks x 256 threads; block owns 8 columns x all 32 batches
// (1 output/thread). W read exactly once from HBM. f64 accumulation keeps the
// mask exact vs the f32 reference (validated absmax=0 in R2-R4).
__global__ __launch_bounds__(256) void mask_kernel(
    const float* __restrict__ A,      // [B,F]
    const float* __restrict__ W,      // [F,N]
    const float* __restrict__ bias,   // [N]
    const float* __restrict__ thr_p,  // [1]
    uint8_t* __restrict__ bits8)      // [B][512]
{
    __shared__ float a_sh[BB * ASTRIDE];   // ~33 KB
    __shared__ float wT[8 * ASTRIDE];      // ~8 KB, [c][f]

    const int t     = threadIdx.x;
    const int chunk = blockIdx.x;          // 0..511
    const int n0    = chunk * 8;

    for (int i = t; i < BB * FF; i += 256) {
        int b = i >> 8, f = i & 255;
        a_sh[b * ASTRIDE + f] = A[i];
    }
    for (int i = t; i < FF * 8; i += 256) {
        int f = i >> 3, c = i & 7;
        wT[c * ASTRIDE + f] = W[(size_t)f * NN + n0 + c];
    }
    __syncthreads();

    const float thr = thr_p[0];
    const int c = t & 7;       // column within chunk
    const int b = t >> 3;      // batch 0..31

    // LDS pattern: ap broadcast per 8-lane group; wp 8 addrs x 8-way
    // broadcast, banks 4c..4c+3 -> all 32 banks, conflict-free.
    const f4* ap = reinterpret_cast<const f4*>(a_sh + b * ASTRIDE);
    const f4* wp = reinterpret_cast<const f4*>(wT   + c * ASTRIDE);

    double s0 = 0.0, s1 = 0.0, s2 = 0.0, s3 = 0.0;
    #pragma unroll 8
    for (int fs = 0; fs < FF / 4; ++fs) {
        f4 a4 = ap[fs];
        f4 w4 = wp[fs];
        s0 = fma((double)a4.x, (double)w4.x, s0);
        s1 = fma((double)a4.y, (double)w4.y, s1);
        s2 = fma((double)a4.z, (double)w4.z, s2);
        s3 = fma((double)a4.w, (double)w4.w, s3);
    }
    const float v = (float)((s0 + s1) + (s2 + s3)) + bias[n0 + c];
    const int m = (fmaxf(v, 0.f) > thr) ? 1 : 0;

    // lane l: bit l of ballot; 8-lane group g=(l>>3) -> byte g.
    unsigned long long bal = __ballot(m);
    if (c == 0) {
        const int g = (t & 63) >> 3;
        bits8[b * 512 + chunk] = (uint8_t)((bal >> (8 * g)) & 0xFF);
    }
}

// ---------------- Kernel 2: fused scan + gather ------------------------------
// Grid (N/RPB = 128, B) x 256 threads = 4096 blocks (2 residency generations).
// Block scans its batch's 256 u16 chunks (512 B, L2-resident), expands its
// 32-row window, then 4 waves each copy/zero 8 rows with 4-deep load batches.
__global__ __launch_bounds__(256) void gather_kernel(
    const float* __restrict__ raw,     // [B,N,D]
    const uint16_t* __restrict__ bits, // [B][256]
    float* __restrict__ out)           // [B,N,D]
{
    const int b   = blockIdx.y;
    const int t   = threadIdx.x;
    const int j0b = blockIdx.x * RPB;

    __shared__ int wsum[4];
    __shared__ int cnt_sh;
    __shared__ int order_sh[RPB];

    // --- per-block scan over packed mask (thread t owns chunk t, 16 cols) ---
    unsigned m = bits[b * 256 + t];
    const int s = __popc(m);

    const int lane = t & 63;
    const int wid  = t >> 6;
    int incl = s;
    #pragma unroll
    for (int d = 1; d < 64; d <<= 1) {
        int x = __shfl_up(incl, d, 64);
        if (lane >= d) incl += x;
    }
    if (lane == 63) wsum[wid] = incl;
    __syncthreads();
    if (t == 0) {
        int run = 0;
        #pragma unroll
        for (int i = 0; i < 4; ++i) { int x = wsum[i]; wsum[i] = run; run += x; }
        cnt_sh = run;
    }
    __syncthreads();

    int base = wsum[wid] + (incl - s);  // stable exclusive prefix for chunk t
    if (base < j0b + RPB && base + s > j0b) {
        const int n0 = t * 16;
        while (m) {
            const int pos = __ffs(m) - 1;
            const unsigned rel = (unsigned)(base - j0b);
            if (rel < RPB) order_sh[rel] = n0 + pos;
            ++base;
            if (base >= j0b + RPB) break;
            m &= m - 1;
        }
    }
    __syncthreads();

    // --- gather/zero: wave wid owns rows j0b + wid*8 .. +7 ---
    const int cnt = cnt_sh;
    const f4* rawb = reinterpret_cast<const f4*>(raw) + (size_t)b * NN * (DD / 4);
    f4*       outb = reinterpret_cast<f4*>(out)       + (size_t)b * NN * (DD / 4);
    const int j0 = j0b + wid * 8;

    #pragma unroll
    for (int g = 0; g < 2; ++g) {
        const int r = j0 + g * 4;
        const int rr = r - j0b;
        f4 v0 = {0.f, 0.f, 0.f, 0.f};
        f4 v1 = {0.f, 0.f, 0.f, 0.f};
        f4 v2 = {0.f, 0.f, 0.f, 0.f};
        f4 v3 = {0.f, 0.f, 0.f, 0.f};
        if (r + 0 < cnt) v0 = rawb[(size_t)order_sh[rr + 0] * (DD / 4) + lane];
        if (r + 1 < cnt) v1 = rawb[(size_t)order_sh[rr + 1] * (DD / 4) + lane];
        if (r + 2 < cnt) v2 = rawb[(size_t)order_sh[rr + 2] * (DD / 4) + lane];
        if (r + 3 < cnt) v3 = rawb[(size_t)order_sh[rr + 3] * (DD / 4) + lane];
        __builtin_nontemporal_store(v0, &outb[(size_t)(r + 0) * (DD / 4) + lane]);
        __builtin_nontemporal_store(v1, &outb[(size_t)(r + 1) * (DD / 4) + lane]);
        __builtin_nontemporal_store(v2, &outb[(size_t)(r + 2) * (DD / 4) + lane]);
        __builtin_nontemporal_store(v3, &outb[(size_t)(r + 3) * (DD / 4) + lane]);
    }
}

extern "C" void kernel_launch(void* const* d_in, const int* in_sizes, int n_in,
                              void* d_out, int out_size, void* d_ws, size_t ws_size,
                              hipStream_t stream) {
    const float* raw  = (const float*)d_in[0];   // [B,N,D]
    const float* A    = (const float*)d_in[1];   // [B,F]
    const float* W    = (const float*)d_in[2];   // [F,N]
    const float* bias = (const float*)d_in[3];   // [N]
    const float* thr  = (const float*)d_in[4];   // [1]
    float* out = (float*)d_out;

    uint8_t* bits8 = (uint8_t*)d_ws;             // B*512 = 16 KB

    mask_kernel<<<512, 256, 0, stream>>>(A, W, bias, thr, bits8);
    gather_kernel<<<dim3(NN / RPB, BB), 256, 0, stream>>>(
        raw, (const uint16_t*)bits8, out);
}